// Round 11
// baseline (487.433 us; speedup 1.0000x reference)
//
#include <hip/hip_runtime.h>
#include <hip/hip_bf16.h>
#include <math.h>

typedef short bf16x8 __attribute__((ext_vector_type(8)));
typedef float f32x4 __attribute__((ext_vector_type(4)));

__device__ __forceinline__ float lrelu(float v) { return v > 0.f ? v : 0.2f * v; }

__device__ __forceinline__ void gload16(const void* g, void* l) {
  __builtin_amdgcn_global_load_lds(
      (const __attribute__((address_space(1))) void*)g,
      (__attribute__((address_space(3))) void*)l, 16, 0, 0);
}

__device__ __forceinline__ uint packbf(float v0, float v1) {
  __hip_bfloat16 h0 = __float2bfloat16(v0);
  __hip_bfloat16 h1 = __float2bfloat16(v1);
  return (uint)(*(unsigned short*)&h0) | ((uint)(*(unsigned short*)&h1) << 16);
}

// ---------------- prep descriptor ----------------
struct PrepArgs {
  const float* W[6]; __hip_bfloat16* Wt[6]; int K[6]; int Nw[6]; int tstart[6];
  int NC, XB;
};

// ---------------- merged: 8-copy degree count (+slots) + time partials + prep ----------
__global__ __launch_bounds__(256) void k_build(
    const int* __restrict__ src, const int* __restrict__ dst, int E,
    int* cntD, int* cntS, int* slotD, int* slotS,
    const float* __restrict__ et, const float* __restrict__ tW1,
    const float* __restrict__ tb1, float* __restrict__ tacc,
    PrepArgs a, const float* __restrict__ x,
    __hip_bfloat16* __restrict__ xbf, __hip_bfloat16* __restrict__ habf,
    __hip_bfloat16* __restrict__ aggbf, int N, int Mp, int EB) {
  __shared__ float se[256];
  __shared__ float buf[256];
  __shared__ float tile[32][65];
  int t = threadIdx.x;
  int bid = blockIdx.x;
  if (bid < EB) {
    int e = bid * 256 + t;
    if (e < E) {
      int d = dst[e], s = src[e];
      int c = bid & 7;                     // copy ≈ XCD id (round-robin dispatch)
      slotD[e] = atomicAdd(&cntD[c * N + d], 1);
      slotS[e] = atomicAdd(&cntS[c * N + s], 1);
    }
    // time-embed partial sums on first 256 blocks
    if (bid < 256) {
      int l = t & 63, w = t >> 6;
      float wk = tW1[l], bk = tb1[l];
      float a0 = 0.f, a1 = 0.f, a2 = 0.f, a3 = 0.f;
      for (int base = bid * 256; base < E; base += 256 * 256) {
        int idx = base + t;
        se[t] = (idx < E) ? et[idx] : 0.f;
        __syncthreads();
        int cnt = E - base; if (cnt > 256) cnt = 256;
        int s0 = w * 64;
        int c2 = cnt - s0; if (c2 < 0) c2 = 0; if (c2 > 64) c2 = 64;
        int j = 0;
        for (; j + 4 <= c2; j += 4) {
          a0 += fmaxf(se[s0 + j] * wk + bk, 0.f);
          a1 += fmaxf(se[s0 + j + 1] * wk + bk, 0.f);
          a2 += fmaxf(se[s0 + j + 2] * wk + bk, 0.f);
          a3 += fmaxf(se[s0 + j + 3] * wk + bk, 0.f);
        }
        for (; j < c2; ++j) a0 += fmaxf(se[s0 + j] * wk + bk, 0.f);
        __syncthreads();
      }
      buf[t] = (a0 + a1) + (a2 + a3);
      __syncthreads();
      if (t < 64) {
        float s = buf[t] + buf[t + 64] + buf[t + 128] + buf[t + 192];
        atomicAdd(&tacc[t], s);
      }
    }
    return;
  }
  int pbid = bid - EB;
  if (pbid < a.NC) {
    int m = 0;
#pragma unroll
    for (int i = 1; i < 6; ++i) if (pbid >= a.tstart[i]) m = i;
    const float* W = a.W[m];
    __hip_bfloat16* Wt = a.Wt[m];
    int K = a.K[m], Nw = a.Nw[m];
    int lt = pbid - a.tstart[m];
    int ntn = Nw >> 6;
    int bk = (lt / ntn) * 32, bn = (lt % ntn) * 64;
    int rn = t & 63, rk = t >> 6;
#pragma unroll
    for (int i = 0; i < 8; ++i)
      tile[rk + i * 4][rn] = W[(size_t)(bk + rk + i * 4) * Nw + bn + rn];
    __syncthreads();
    int wk2 = (t & 15) * 2, wn = t >> 4;
    uint* Wo = (uint*)Wt;
#pragma unroll
    for (int i = 0; i < 4; ++i) {
      int n = wn + i * 16;
      Wo[((size_t)(bn + n) * K + bk + wk2) >> 1] = packbf(tile[wk2][n], tile[wk2 + 1][n]);
    }
  } else if (pbid < a.NC + a.XB) {
    int i4 = (pbid - a.NC) * 256 + t;
    int row = i4 >> 4;
    float4 v = make_float4(0.f, 0.f, 0.f, 0.f);
    if (row < N) v = ((const float4*)x)[i4];
    uint2 p; p.x = packbf(v.x, v.y); p.y = packbf(v.z, v.w);
    ((uint2*)xbf)[i4] = p;
  } else {
    int row = N + (pbid - a.NC - a.XB);
    ((uint*)habf)[(size_t)row * 256 + t] = 0;
    if (t < 64) ((uint*)aggbf)[(size_t)row * 64 + t] = 0;
  }
}

// ---------------- scans over 8-copy counts (blocks 0,1) + time-combine (block 2) --------
// Emits off[] (node offsets) and coff[c][node] (per-copy base) for atomic-free fill.
__global__ __launch_bounds__(1024) void k_scan2c(
    const int* __restrict__ cntD, int* __restrict__ offD, int* __restrict__ coffD,
    const int* __restrict__ cntS, int* __restrict__ offS, int* __restrict__ coffS,
    int n,
    const float* __restrict__ tacc, const float* __restrict__ tW2,
    const float* __restrict__ tb2, const float* __restrict__ fW1,
    const float* __restrict__ fb1, float* __restrict__ cvec, int E) {
  int t = threadIdx.x;
  if (blockIdx.x == 2) {
    __shared__ float tm[128];
    if (t < 128) {
      float inv = 1.f / (float)E;
      float acc = tb2[t];
      for (int k = 0; k < 64; ++k) acc += (tacc[k] * inv) * tW2[k * 128 + t];
      tm[t] = acc;
    }
    __syncthreads();
    if (t < 128) {
      float c = fb1[t];
      for (int k = 0; k < 128; ++k) c += tm[k] * fW1[(128 + k) * 128 + t];
      cvec[t] = c;
    }
    return;
  }
  const int* cnt = blockIdx.x ? cntS : cntD;
  int* off = blockIdx.x ? offS : offD;
  int* coff = blockIdx.x ? coffS : coffD;
  __shared__ int sums[1024];
  int PT = (n + 1023) >> 10;
  int start = t * PT;
  int local = 0;
  for (int i = 0; i < PT; ++i) {
    int idx = start + i;
    if (idx < n) {
#pragma unroll
      for (int c = 0; c < 8; ++c) local += cnt[c * n + idx];
    }
  }
  sums[t] = local;
  __syncthreads();
  for (int o = 1; o < 1024; o <<= 1) {
    int v = (t >= o) ? sums[t - o] : 0;
    __syncthreads();
    sums[t] += v;
    __syncthreads();
  }
  int run = sums[t] - local;
  for (int i = 0; i < PT; ++i) {
    int idx = start + i;
    if (idx < n) {
      off[idx] = run;
      int acc = run;
#pragma unroll
      for (int c = 0; c < 8; ++c) {
        int v = cnt[c * n + idx];
        coff[c * n + idx] = acc;
        acc += v;
      }
      run = acc;
    }
  }
  if (t == 1023) off[n] = run;
}

// ---------------- bf16 MFMA GEMM, BK=64, EPI1 epilogue, optional embedded CSR-fill ----
// blocks with blockIdx.x >= TBx and blockIdx.y == 0 perform the (atomic-free) fill.
__global__ __launch_bounds__(256) void gemm_e1(
    const __hip_bfloat16* __restrict__ A, const __hip_bfloat16* __restrict__ Bt,
    void* __restrict__ Cout, int M, int Nn, int K,
    const float* __restrict__ asrc, const float* __restrict__ adst,
    float* __restrict__ al, float* __restrict__ ar,
    float* __restrict__ C2, const float* __restrict__ bias2,
    int TBx,
    const int* __restrict__ fsrc, const int* __restrict__ fdst, int fE,
    const int* __restrict__ fcoffD, const int* __restrict__ fslotD, int* flstD,
    const int* __restrict__ fcoffS, const int* __restrict__ fslotS, int* flstS)
{
  __shared__ short As0[128 * 32];
  __shared__ short As1[128 * 32];
  __shared__ short Bs0[128 * 32];
  __shared__ short Bs1[128 * 32];
  if ((int)blockIdx.x >= TBx) {
    if (blockIdx.y == 0) {
      int e = ((int)blockIdx.x - TBx) * 256 + (int)threadIdx.x;
      if (e < fE) {
        int d = fdst[e], s = fsrc[e];
        int c = (e >> 8) & 7;
        flstD[fcoffD[c * Nn + d] + fslotD[e]] = s;
        flstS[fcoffS[c * Nn + s] + fslotS[e]] = d;
      }
    }
    return;
  }
  int tid = threadIdx.x;
  int bm = blockIdx.x * 128;
  int cb = blockIdx.y;
  int bn = cb * 128;
  int w = tid >> 6, l = tid & 63;
  int wr = (w >> 1) * 64, wc = (w & 1) * 64;
  f32x4 acc[4][4] = {};
  const short* Ag = (const short*)A;
  const short* Bg = (const short*)Bt;

  for (int k0 = 0; k0 < K; k0 += 64) {
#pragma unroll
    for (int i = 0; i < 2; ++i) {
      int slot = i * 256 + tid;
      int row = slot >> 2;
      int col = (slot & 3) * 8;
      const short* Arow = Ag + (size_t)(bm + row) * K + k0 + col;
      const short* Brow = Bg + (size_t)(bn + row) * K + k0 + col;
      gload16(Arow, &As0[slot * 8]);
      gload16(Arow + 32, &As1[slot * 8]);
      gload16(Brow, &Bs0[slot * 8]);
      gload16(Brow + 32, &Bs1[slot * 8]);
    }
    __syncthreads();
    {
      bf16x8 af[4], bfr[4];
#pragma unroll
      for (int m = 0; m < 4; ++m)
        af[m] = *(const bf16x8*)&As0[(wr + m * 16 + (l & 15)) * 32 + (l >> 4) * 8];
#pragma unroll
      for (int n = 0; n < 4; ++n)
        bfr[n] = *(const bf16x8*)&Bs0[(wc + n * 16 + (l & 15)) * 32 + (l >> 4) * 8];
#pragma unroll
      for (int m = 0; m < 4; ++m)
#pragma unroll
        for (int n = 0; n < 4; ++n)
          acc[m][n] = __builtin_amdgcn_mfma_f32_16x16x32_bf16(af[m], bfr[n], acc[m][n], 0, 0, 0);
    }
    {
      bf16x8 af[4], bfr[4];
#pragma unroll
      for (int m = 0; m < 4; ++m)
        af[m] = *(const bf16x8*)&As1[(wr + m * 16 + (l & 15)) * 32 + (l >> 4) * 8];
#pragma unroll
      for (int n = 0; n < 4; ++n)
        bfr[n] = *(const bf16x8*)&Bs1[(wc + n * 16 + (l & 15)) * 32 + (l >> 4) * 8];
#pragma unroll
      for (int m = 0; m < 4; ++m)
#pragma unroll
        for (int n = 0; n < 4; ++n)
          acc[m][n] = __builtin_amdgcn_mfma_f32_16x16x32_bf16(af[m], bfr[n], acc[m][n], 0, 0, 0);
    }
    __syncthreads();
  }

  int g = l >> 4, cc = l & 15, cr = g * 4;

  if (cb < 4) {
#pragma unroll
    for (int n = 0; n < 4; ++n) {
      int col = bn + wc + n * 16 + cc;
#pragma unroll
      for (int m = 0; m < 4; ++m) {
#pragma unroll
        for (int r = 0; r < 4; ++r) {
          int gm = bm + wr + m * 16 + cr + r;
          if (gm < M)
            ((__hip_bfloat16*)Cout)[(size_t)gm * 512 + col] = __float2bfloat16(acc[m][n][r]);
        }
      }
    }
    // fused al/ar dots for head h = cb
    float asv[4], adv[4];
#pragma unroll
    for (int n = 0; n < 4; ++n) {
      int ch = bn + wc + n * 16 + cc;
      asv[n] = asrc[ch]; adv[n] = adst[ch];
    }
    float* spal = (float*)As0;
    float* spar = spal + 256;
#pragma unroll
    for (int m = 0; m < 4; ++m) {
#pragma unroll
      for (int r = 0; r < 4; ++r) {
        float pa = acc[m][0][r] * asv[0] + acc[m][1][r] * asv[1]
                 + acc[m][2][r] * asv[2] + acc[m][3][r] * asv[3];
        float pb = acc[m][0][r] * adv[0] + acc[m][1][r] * adv[1]
                 + acc[m][2][r] * adv[2] + acc[m][3][r] * adv[3];
#pragma unroll
        for (int o = 1; o < 16; o <<= 1) {
          pa += __shfl_xor(pa, o);
          pb += __shfl_xor(pb, o);
        }
        if (cc == 0) {
          int rl = m * 16 + cr + r;
          spal[w * 64 + rl] = pa;
          spar[w * 64 + rl] = pb;
        }
      }
    }
    __syncthreads();
    if ((w & 1) == 0) {
      float av = spal[w * 64 + l] + spal[(w + 1) * 64 + l];
      float rv = spar[w * 64 + l] + spar[(w + 1) * 64 + l];
      int row = bm + wr + l;
      if (row < Nn) { al[row * 4 + cb] = av; ar[row * 4 + cb] = rv; }
    }
  } else {
#pragma unroll
    for (int n = 0; n < 4; ++n) {
      int col2 = wc + n * 16 + cc;
      float bb = bias2[col2];
#pragma unroll
      for (int m = 0; m < 4; ++m) {
#pragma unroll
        for (int r = 0; r < 4; ++r) {
          int gm = bm + wr + m * 16 + cr + r;
          if (gm < Nn) C2[(size_t)gm * 128 + col2] = acc[m][n][r] + bb;
        }
      }
    }
  }
}

// ---------------- fused final MLP: z1 = relu(A@F1+cvec); z2 = z1@F2+fb2; LN; += resid ----
__global__ __launch_bounds__(256) void gemm_ff(
    const __hip_bfloat16* __restrict__ A, const __hip_bfloat16* __restrict__ B1t,
    const __hip_bfloat16* __restrict__ B2t, const float* __restrict__ cvec,
    const float* __restrict__ fb2, const float* __restrict__ lng,
    const float* __restrict__ lnb, float* __restrict__ resid, int M)
{
  __shared__ char ldsraw[32768 + 128 * 136 * 2];
  short* As0 = (short*)ldsraw;
  short* As1 = As0 + 4096;
  short* Bs0 = As1 + 4096;
  short* Bs1 = Bs0 + 4096;
  short* z1s = (short*)(ldsraw + 32768);   // [128][136] bf16
  int tid = threadIdx.x;
  int bm = blockIdx.x * 128;
  int w = tid >> 6, l = tid & 63;
  int wr = (w >> 1) * 64, wc = (w & 1) * 64;
  int g = l >> 4, cc = l & 15, cr = g * 4;
  const short* Ag = (const short*)A;
  const short* B1 = (const short*)B1t;
  const short* B2 = (const short*)B2t;
  f32x4 acc[4][4] = {};

  for (int k0 = 0; k0 < 128; k0 += 64) {
#pragma unroll
    for (int i = 0; i < 2; ++i) {
      int slot = i * 256 + tid;
      int row = slot >> 2;
      int col = (slot & 3) * 8;
      const short* Arow = Ag + (size_t)(bm + row) * 128 + k0 + col;
      const short* Brow = B1 + (size_t)row * 128 + k0 + col;
      gload16(Arow, &As0[slot * 8]);
      gload16(Arow + 32, &As1[slot * 8]);
      gload16(Brow, &Bs0[slot * 8]);
      gload16(Brow + 32, &Bs1[slot * 8]);
    }
    __syncthreads();
    {
      bf16x8 af[4], bfr[4];
#pragma unroll
      for (int m = 0; m < 4; ++m)
        af[m] = *(const bf16x8*)&As0[(wr + m * 16 + (l & 15)) * 32 + (l >> 4) * 8];
#pragma unroll
      for (int n = 0; n < 4; ++n)
        bfr[n] = *(const bf16x8*)&Bs0[(wc + n * 16 + (l & 15)) * 32 + (l >> 4) * 8];
#pragma unroll
      for (int m = 0; m < 4; ++m)
#pragma unroll
        for (int n = 0; n < 4; ++n)
          acc[m][n] = __builtin_amdgcn_mfma_f32_16x16x32_bf16(af[m], bfr[n], acc[m][n], 0, 0, 0);
    }
    {
      bf16x8 af[4], bfr[4];
#pragma unroll
      for (int m = 0; m < 4; ++m)
        af[m] = *(const bf16x8*)&As1[(wr + m * 16 + (l & 15)) * 32 + (l >> 4) * 8];
#pragma unroll
      for (int n = 0; n < 4; ++n)
        bfr[n] = *(const bf16x8*)&Bs1[(wc + n * 16 + (l & 15)) * 32 + (l >> 4) * 8];
#pragma unroll
      for (int m = 0; m < 4; ++m)
#pragma unroll
        for (int n = 0; n < 4; ++n)
          acc[m][n] = __builtin_amdgcn_mfma_f32_16x16x32_bf16(af[m], bfr[n], acc[m][n], 0, 0, 0);
    }
    __syncthreads();
  }

#pragma unroll
  for (int n = 0; n < 4; ++n) {
    int col = wc + n * 16 + cc;
    float bb = cvec[col];
#pragma unroll
    for (int m = 0; m < 4; ++m) {
#pragma unroll
      for (int r = 0; r < 4; ++r) {
        int rl = wr + m * 16 + cr + r;
        float v = fmaxf(acc[m][n][r] + bb, 0.f);
        __hip_bfloat16 hb = __float2bfloat16(v);
        z1s[rl * 136 + col] = *(short*)&hb;
      }
    }
  }
#pragma unroll
  for (int m = 0; m < 4; ++m)
#pragma unroll
    for (int n = 0; n < 4; ++n)
      acc[m][n] = (f32x4){0.f, 0.f, 0.f, 0.f};
  __syncthreads();

  for (int k0 = 0; k0 < 128; k0 += 64) {
#pragma unroll
    for (int i = 0; i < 2; ++i) {
      int slot = i * 256 + tid;
      int row = slot >> 2;
      int col = (slot & 3) * 8;
      const short* Brow = B2 + (size_t)row * 128 + k0 + col;
      gload16(Brow, &Bs0[slot * 8]);
      gload16(Brow + 32, &Bs1[slot * 8]);
    }
    __syncthreads();
    {
      bf16x8 af[4], bfr[4];
#pragma unroll
      for (int m = 0; m < 4; ++m)
        af[m] = *(const bf16x8*)&z1s[(wr + m * 16 + (l & 15)) * 136 + k0 + (l >> 4) * 8];
#pragma unroll
      for (int n = 0; n < 4; ++n)
        bfr[n] = *(const bf16x8*)&Bs0[(wc + n * 16 + (l & 15)) * 32 + (l >> 4) * 8];
#pragma unroll
      for (int m = 0; m < 4; ++m)
#pragma unroll
        for (int n = 0; n < 4; ++n)
          acc[m][n] = __builtin_amdgcn_mfma_f32_16x16x32_bf16(af[m], bfr[n], acc[m][n], 0, 0, 0);
    }
    {
      bf16x8 af[4], bfr[4];
#pragma unroll
      for (int m = 0; m < 4; ++m)
        af[m] = *(const bf16x8*)&z1s[(wr + m * 16 + (l & 15)) * 136 + k0 + 32 + (l >> 4) * 8];
#pragma unroll
      for (int n = 0; n < 4; ++n)
        bfr[n] = *(const bf16x8*)&Bs1[(wc + n * 16 + (l & 15)) * 32 + (l >> 4) * 8];
#pragma unroll
      for (int m = 0; m < 4; ++m)
#pragma unroll
        for (int n = 0; n < 4; ++n)
          acc[m][n] = __builtin_amdgcn_mfma_f32_16x16x32_bf16(af[m], bfr[n], acc[m][n], 0, 0, 0);
    }
    __syncthreads();
  }

  float bb[4], gl_[4], gb_[4];
#pragma unroll
  for (int n = 0; n < 4; ++n) {
    int col = wc + n * 16 + cc;
    bb[n] = fb2[col]; gl_[n] = lng[col]; gb_[n] = lnb[col];
  }
  float* ssum = (float*)As0;
  float* ssq = ssum + 256;
  float* smu = ssum + 512;
  float* srs = ssum + 640;
#pragma unroll
  for (int m = 0; m < 4; ++m) {
#pragma unroll
    for (int r = 0; r < 4; ++r) {
      float s = 0.f, q = 0.f;
#pragma unroll
      for (int n = 0; n < 4; ++n) {
        float z = acc[m][n][r] + bb[n];
        s += z; q += z * z;
      }
#pragma unroll
      for (int o = 1; o < 16; o <<= 1) {
        s += __shfl_xor(s, o);
        q += __shfl_xor(q, o);
      }
      if (cc == 0) {
        int rl = m * 16 + cr + r;
        ssum[w * 64 + rl] = s;
        ssq[w * 64 + rl] = q;
      }
    }
  }
  __syncthreads();
  if ((w & 1) == 0) {
    float s = ssum[w * 64 + l] + ssum[(w + 1) * 64 + l];
    float q = ssq[w * 64 + l] + ssq[(w + 1) * 64 + l];
    float mu = s * (1.f / 128.f);
    float var = q * (1.f / 128.f) - mu * mu;
    smu[wr + l] = mu;
    srs[wr + l] = rsqrtf(var + 1e-5f);
  }
  __syncthreads();
#pragma unroll
  for (int m = 0; m < 4; ++m) {
#pragma unroll
    for (int r = 0; r < 4; ++r) {
      int rl = wr + m * 16 + cr + r;
      int gm = bm + rl;
      if (gm < M) {
        float mu = smu[rl], rs = srs[rl];
#pragma unroll
        for (int n = 0; n < 4; ++n) {
          int col = wc + n * 16 + cc;
          float z = acc[m][n][r] + bb[n];
          float y = (z - mu) * rs * gl_[n] + gb_[n] + resid[(size_t)gm * 128 + col];
          resid[(size_t)gm * 128 + col] = y;
        }
      }
    }
  }
}

// ---------------- GAT aggregation: wave per dst node, full-row uint4 gather ----------------
__global__ __launch_bounds__(256) void k_gat_agg(
    const __hip_bfloat16* __restrict__ xl, const float* __restrict__ al,
    const float* __restrict__ ar, const int* __restrict__ off,
    const int* __restrict__ lst, const float* __restrict__ bias,
    __hip_bfloat16* __restrict__ outb, __hip_bfloat16* __restrict__ outh,
    int mode, int N)
{
  __shared__ int   sside[4][64];
  __shared__ float sebuf[4][4][68];
  int w = threadIdx.x >> 6, l = threadIdx.x & 63;
  int d = blockIdx.x * 4 + w;
  bool active = (d < N);
  int base = 0, deg = 0, tot = 0;
  float4 arv = make_float4(0.f, 0.f, 0.f, 0.f);
  if (active) {
    base = off[d]; deg = off[d + 1] - base; tot = deg + 1;
    arv = *(const float4*)(ar + 4 * d);
  }
  int hh = l >> 4;
  float facc[8] = {0.f, 0.f, 0.f, 0.f, 0.f, 0.f, 0.f, 0.f};
  float dn0 = 0.f, dn1 = 0.f, dn2 = 0.f, dn3 = 0.f;
  const uint4* xw = (const uint4*)xl;
  auto fma8 = [&](uint4 pv, float e) {
    facc[0] += e * __uint_as_float(pv.x << 16);
    facc[1] += e * __uint_as_float(pv.x & 0xffff0000u);
    facc[2] += e * __uint_as_float(pv.y << 16);
    facc[3] += e * __uint_as_float(pv.y & 0xffff0000u);
    facc[4] += e * __uint_as_float(pv.z << 16);
    facc[5] += e * __uint_as_float(pv.z & 0xffff0000u);
    facc[6] += e * __uint_as_float(pv.w << 16);
    facc[7] += e * __uint_as_float(pv.w & 0xffff0000u);
  };
  for (int cb = 0; cb < tot; cb += 64) {
    int j = cb + l;
    float e0 = 0.f, e1 = 0.f, e2 = 0.f, e3 = 0.f;
    int sid = 0;
    if (j < tot) {
      sid = (j == deg) ? d : lst[base + j];
      float4 av = *(const float4*)(al + 4 * sid);
      e0 = __expf(lrelu(av.x + arv.x));
      e1 = __expf(lrelu(av.y + arv.y));
      e2 = __expf(lrelu(av.z + arv.z));
      e3 = __expf(lrelu(av.w + arv.w));
      dn0 += e0; dn1 += e1; dn2 += e2; dn3 += e3;
    }
    sside[w][l] = sid;
    sebuf[w][0][l] = e0; sebuf[w][1][l] = e1;
    sebuf[w][2][l] = e2; sebuf[w][3][l] = e3;
    int cnt = tot - cb; if (cnt > 64) cnt = 64;
    int jj = 0;
    for (; jj + 4 <= cnt; jj += 4) {
      int s0 = sside[w][jj], s1 = sside[w][jj + 1];
      int s2 = sside[w][jj + 2], s3 = sside[w][jj + 3];
      float ea = sebuf[w][hh][jj], eb = sebuf[w][hh][jj + 1];
      float ec = sebuf[w][hh][jj + 2], ed = sebuf[w][hh][jj + 3];
      uint4 p0 = xw[(size_t)s0 * 64 + l];
      uint4 p1 = xw[(size_t)s1 * 64 + l];
      uint4 p2 = xw[(size_t)s2 * 64 + l];
      uint4 p3 = xw[(size_t)s3 * 64 + l];
      fma8(p0, ea); fma8(p1, eb); fma8(p2, ec); fma8(p3, ed);
    }
    for (; jj < cnt; ++jj) {
      int s0 = sside[w][jj];
      float ea = sebuf[w][hh][jj];
      uint4 p0 = xw[(size_t)s0 * 64 + l];
      fma8(p0, ea);
    }
  }
#pragma unroll
  for (int o = 1; o < 64; o <<= 1) {
    dn0 += __shfl_xor(dn0, o); dn1 += __shfl_xor(dn1, o);
    dn2 += __shfl_xor(dn2, o); dn3 += __shfl_xor(dn3, o);
  }
  if (!active) return;
  float dsel = hh == 0 ? dn0 : hh == 1 ? dn1 : hh == 2 ? dn2 : dn3;
  float rden = 1.f / dsel;
  if (mode == 0) {
    int c8 = l * 8;
    const float4* bp = (const float4*)(bias + c8);
    float4 b0 = bp[0], b1 = bp[1];
    float vb[8] = {b0.x, b0.y, b0.z, b0.w, b1.x, b1.y, b1.z, b1.w};
    uint4 o4; uint* po = (uint*)&o4;
#pragma unroll
    for (int i = 0; i < 4; ++i) {
      float v0 = fmaxf(facc[2*i]   * rden + vb[2*i],   0.f);
      float v1 = fmaxf(facc[2*i+1] * rden + vb[2*i+1], 0.f);
      po[i] = packbf(v0, v1);
    }
    ((uint4*)outb)[(size_t)d * 64 + l] = o4;
  } else {
#pragma unroll
    for (int i = 0; i < 8; ++i) {
      facc[i] *= rden;
      facc[i] += __shfl_xor(facc[i], 16);
      facc[i] += __shfl_xor(facc[i], 32);
    }
    if (l < 16) {
      int c = l * 8;
      const float4* bp = (const float4*)(bias + c);
      float4 b0 = bp[0], b1 = bp[1];
      float vb[8] = {b0.x, b0.y, b0.z, b0.w, b1.x, b1.y, b1.z, b1.w};
      uint4 o4; uint* po = (uint*)&o4;
#pragma unroll
      for (int i = 0; i < 4; ++i) {
        float v0 = fmaxf(facc[2*i]   * 0.25f + vb[2*i],   0.f);
        float v1 = fmaxf(facc[2*i+1] * 0.25f + vb[2*i+1], 0.f);
        po[i] = packbf(v0, v1);
      }
      ((uint4*)outh)[(size_t)d * 16 + l] = o4;
    }
  }
}

// ---------------- final src-side segment sum (h3 bf16 -> aggbf bf16), 4-deep ----------------
__global__ __launch_bounds__(256) void k_aggsrc(const __hip_bfloat16* __restrict__ h3,
    const int* __restrict__ off, const int* __restrict__ lst,
    __hip_bfloat16* __restrict__ out, int N) {
  int w = threadIdx.x >> 6, l = threadIdx.x & 63;
  int n = blockIdx.x * 4 + w;
  if (n >= N) return;
  const uint* hw = (const uint*)h3;
  uint pv = hw[(size_t)n * 64 + l];
  float a0 = __uint_as_float(pv << 16);
  float a1 = __uint_as_float(pv & 0xffff0000u);
  float b0 = 0.f, b1 = 0.f, c0 = 0.f, c1 = 0.f, d0 = 0.f, d1 = 0.f;
  int b = off[n], e = off[n + 1];
  int j = b;
  for (; j + 4 <= e; j += 4) {
    int s0 = lst[j], s1 = lst[j + 1], s2 = lst[j + 2], s3 = lst[j + 3];
    uint q0 = hw[(size_t)s0 * 64 + l];
    uint q1 = hw[(size_t)s1 * 64 + l];
    uint q2 = hw[(size_t)s2 * 64 + l];
    uint q3 = hw[(size_t)s3 * 64 + l];
    a0 += __uint_as_float(q0 << 16); a1 += __uint_as_float(q0 & 0xffff0000u);
    b0 += __uint_as_float(q1 << 16); b1 += __uint_as_float(q1 & 0xffff0000u);
    c0 += __uint_as_float(q2 << 16); c1 += __uint_as_float(q2 & 0xffff0000u);
    d0 += __uint_as_float(q3 << 16); d1 += __uint_as_float(q3 & 0xffff0000u);
  }
  for (; j < e; ++j) {
    uint q = hw[(size_t)lst[j] * 64 + l];
    a0 += __uint_as_float(q << 16);
    a1 += __uint_as_float(q & 0xffff0000u);
  }
  ((uint*)out)[(size_t)n * 64 + l] = packbf((a0 + b0) + (c0 + d0), (a1 + b1) + (c1 + d1));
}

extern "C" void kernel_launch(void* const* d_in, const int* in_sizes, int n_in,
                              void* d_out, int out_size, void* d_ws, size_t ws_size,
                              hipStream_t stream) {
  (void)n_in; (void)out_size; (void)ws_size;
  const float* x   = (const float*)d_in[0];
  const float* et  = (const float*)d_in[1];
  const float* W1  = (const float*)d_in[2];
  const float* as1 = (const float*)d_in[3];
  const float* ad1 = (const float*)d_in[4];
  const float* b1  = (const float*)d_in[5];
  const float* W2  = (const float*)d_in[6];
  const float* as2 = (const float*)d_in[7];
  const float* ad2 = (const float*)d_in[8];
  const float* b2  = (const float*)d_in[9];
  const float* W3  = (const float*)d_in[10];
  const float* as3 = (const float*)d_in[11];
  const float* ad3 = (const float*)d_in[12];
  const float* b3  = (const float*)d_in[13];
  const float* tW1 = (const float*)d_in[14];
  const float* tb1 = (const float*)d_in[15];
  const float* tW2 = (const float*)d_in[16];
  const float* tb2 = (const float*)d_in[17];
  const float* fW1 = (const float*)d_in[18];
  const float* fb1 = (const float*)d_in[19];
  const float* fW2 = (const float*)d_in[20];
  const float* fb2 = (const float*)d_in[21];
  const float* lng = (const float*)d_in[22];
  const float* lnb = (const float*)d_in[23];
  const float* rW  = (const float*)d_in[24];
  const float* rb  = (const float*)d_in[25];
  const int*   ei  = (const int*)d_in[26];
  const int N = in_sizes[0] / 64;     // 20000
  const int E = in_sizes[26] / 2;     // 320000
  const int Mp = ((N + 127) / 128) * 128;  // 20096
  const int* src = ei;
  const int* dst = ei + E;

  char* cur = (char*)d_ws;
  auto carve = [&](size_t bytes) { char* p = cur; cur += (bytes + 255) & ~(size_t)255; return p; };
  __hip_bfloat16* xbf  = (__hip_bfloat16*)carve((size_t)Mp * 64 * 2);
  __hip_bfloat16* habf = (__hip_bfloat16*)carve((size_t)Mp * 512 * 2);
  __hip_bfloat16* xlbf = (__hip_bfloat16*)carve((size_t)Mp * 512 * 2);
  __hip_bfloat16* wtCat= (__hip_bfloat16*)carve((size_t)640 * 64 * 2);  // [W1t(512); rWt(128)]
  __hip_bfloat16* wt2  = (__hip_bfloat16*)carve((size_t)512 * 512 * 2);
  __hip_bfloat16* wt3  = (__hip_bfloat16*)carve((size_t)512 * 512 * 2);
  __hip_bfloat16* wtF1 = (__hip_bfloat16*)carve((size_t)128 * 128 * 2);
  __hip_bfloat16* wtF2 = (__hip_bfloat16*)carve((size_t)128 * 128 * 2);
  __hip_bfloat16* aggbf= (__hip_bfloat16*)carve((size_t)Mp * 128 * 2);
  __hip_bfloat16* h3   = (__hip_bfloat16*)carve((size_t)N * 128 * 2);
  float* al   = (float*)carve((size_t)N * 4 * 4);
  float* ar   = (float*)carve((size_t)N * 4 * 4);
  float* cvec = (float*)carve(128 * 4);
  int* offD = (int*)carve((size_t)(N + 1) * 4);
  int* offS = (int*)carve((size_t)(N + 1) * 4);
  int* lstD = (int*)carve((size_t)E * 4);
  int* lstS = (int*)carve((size_t)E * 4);
  int* slotD = (int*)carve((size_t)E * 4);
  int* slotS = (int*)carve((size_t)E * 4);
  int* coffD = (int*)carve((size_t)8 * N * 4);
  int* coffS = (int*)carve((size_t)8 * N * 4);
  char* zstart = cur;
  int* cntD = (int*)carve((size_t)8 * N * 4);
  int* cntS = (int*)carve((size_t)8 * N * 4);
  float* tacc = (float*)carve(64 * 4);
  size_t zbytes = (size_t)(cur - zstart);
  float* xres = (float*)d_out;

  hipMemsetAsync(zstart, 0, zbytes, stream);

  const int EB = (E + 255) / 256;   // 1250
  // merged: 8-copy count (+slots) + time partials + weight prep + x conv + pad zero
  PrepArgs pa;
  {
    int ts = 0;
    auto setd = [&](int i, const float* W, __hip_bfloat16* Wt, int K, int Nw) {
      pa.W[i] = W; pa.Wt[i] = Wt; pa.K[i] = K; pa.Nw[i] = Nw; pa.tstart[i] = ts;
      ts += (K / 32) * (Nw / 64);
    };
    setd(0, W1, wtCat, 64, 512);
    setd(1, W2, wt2, 512, 512);
    setd(2, W3, wt3, 512, 512);
    setd(3, rW, wtCat + (size_t)512 * 64, 64, 128);
    setd(4, fW1, wtF1, 128, 128);
    setd(5, fW2, wtF2, 128, 128);
    pa.NC = ts;
    pa.XB = Mp / 16;
    int grid = EB + pa.NC + pa.XB + (Mp - N);
    k_build<<<grid, 256, 0, stream>>>(src, dst, E, cntD, cntS, slotD, slotS,
                                      et, tW1, tb1, tacc,
                                      pa, x, xbf, habf, aggbf, N, Mp, EB);
  }
  k_scan2c<<<3, 1024, 0, stream>>>(cntD, offD, coffD, cntS, offS, coffS, N,
                                   tacc, tW2, tb2, fW1, fb1, cvec, E);

  const int TB = Mp / 128;  // 157
  const int GB = (N + 3) / 4;
  const int BIG = 1 << 30;

  // layer 1 GEMM (+x_res in col-block 4) with embedded atomic-free CSR fill
  gemm_e1<<<dim3(TB + EB, 5), 256, 0, stream>>>(xbf, wtCat, xlbf, Mp, N, 64,
      as1, ad1, al, ar, xres, rb,
      TB, src, dst, E, coffD, slotD, lstD, coffS, slotS, lstS);
  k_gat_agg<<<GB, 256, 0, stream>>>(xlbf, al, ar, offD, lstD, b1, habf, nullptr, 0, N);
  // layer 2
  gemm_e1<<<dim3(TB, 4), 256, 0, stream>>>(habf, wt2, xlbf, Mp, N, 512,
      as2, ad2, al, ar, nullptr, nullptr,
      BIG, nullptr, nullptr, 0, nullptr, nullptr, nullptr, nullptr, nullptr, nullptr);
  k_gat_agg<<<GB, 256, 0, stream>>>(xlbf, al, ar, offD, lstD, b2, habf, nullptr, 0, N);
  // layer 3 (head-mean -> h3)
  gemm_e1<<<dim3(TB, 4), 256, 0, stream>>>(habf, wt3, xlbf, Mp, N, 512,
      as3, ad3, al, ar, nullptr, nullptr,
      BIG, nullptr, nullptr, 0, nullptr, nullptr, nullptr, nullptr, nullptr, nullptr);
  k_gat_agg<<<GB, 256, 0, stream>>>(xlbf, al, ar, offD, lstD, b3, nullptr, h3, 1, N);

  // agg = segment_sum(h3[dst], src)
  k_aggsrc<<<GB, 256, 0, stream>>>(h3, offS, lstS, aggbf, N);

  // fused final MLP + LN + residual -> d_out
  gemm_ff<<<TB, 256, 0, stream>>>(aggbf, wtF1, wtF2, cvec, fb2, lng, lnb, xres, N);
}

// Round 12
// 347.703 us; speedup vs baseline: 1.4019x; 1.4019x over previous
//
#include <hip/hip_runtime.h>
#include <hip/hip_bf16.h>
#include <math.h>

typedef short bf16x8 __attribute__((ext_vector_type(8)));
typedef float f32x4 __attribute__((ext_vector_type(4)));

__device__ __forceinline__ float lrelu(float v) { return v > 0.f ? v : 0.2f * v; }

__device__ __forceinline__ void gload16(const void* g, void* l) {
  __builtin_amdgcn_global_load_lds(
      (const __attribute__((address_space(1))) void*)g,
      (__attribute__((address_space(3))) void*)l, 16, 0, 0);
}

__device__ __forceinline__ uint packbf(float v0, float v1) {
  __hip_bfloat16 h0 = __float2bfloat16(v0);
  __hip_bfloat16 h1 = __float2bfloat16(v1);
  return (uint)(*(unsigned short*)&h0) | ((uint)(*(unsigned short*)&h1) << 16);
}

// ---------------- prep descriptor ----------------
struct PrepArgs {
  const float* W[6]; __hip_bfloat16* Wt[6]; int K[6]; int Nw[6]; int tstart[6];
  int NC, XB;
};

// ---------------- merged: 8-copy degree count (+slots) + time partials + prep ----------
__global__ __launch_bounds__(256) void k_build(
    const int* __restrict__ src, const int* __restrict__ dst, int E,
    int* cntD, int* cntS, int* slotD, int* slotS,
    const float* __restrict__ et, const float* __restrict__ tW1,
    const float* __restrict__ tb1, float* __restrict__ tacc,
    PrepArgs a, const float* __restrict__ x,
    __hip_bfloat16* __restrict__ xbf, __hip_bfloat16* __restrict__ habf,
    __hip_bfloat16* __restrict__ aggbf, int N, int Mp, int EB) {
  __shared__ float se[256];
  __shared__ float buf[256];
  __shared__ float tile[32][65];
  int t = threadIdx.x;
  int bid = blockIdx.x;
  if (bid < EB) {
    int e = bid * 256 + t;
    if (e < E) {
      int d = dst[e], s = src[e];
      int c = bid & 7;                     // copy ≈ XCD id (round-robin dispatch)
      slotD[e] = atomicAdd(&cntD[c * N + d], 1);
      slotS[e] = atomicAdd(&cntS[c * N + s], 1);
    }
    if (bid < 256) {
      int l = t & 63, w = t >> 6;
      float wk = tW1[l], bk = tb1[l];
      float a0 = 0.f, a1 = 0.f, a2 = 0.f, a3 = 0.f;
      for (int base = bid * 256; base < E; base += 256 * 256) {
        int idx = base + t;
        se[t] = (idx < E) ? et[idx] : 0.f;
        __syncthreads();
        int cnt = E - base; if (cnt > 256) cnt = 256;
        int s0 = w * 64;
        int c2 = cnt - s0; if (c2 < 0) c2 = 0; if (c2 > 64) c2 = 64;
        int j = 0;
        for (; j + 4 <= c2; j += 4) {
          a0 += fmaxf(se[s0 + j] * wk + bk, 0.f);
          a1 += fmaxf(se[s0 + j + 1] * wk + bk, 0.f);
          a2 += fmaxf(se[s0 + j + 2] * wk + bk, 0.f);
          a3 += fmaxf(se[s0 + j + 3] * wk + bk, 0.f);
        }
        for (; j < c2; ++j) a0 += fmaxf(se[s0 + j] * wk + bk, 0.f);
        __syncthreads();
      }
      buf[t] = (a0 + a1) + (a2 + a3);
      __syncthreads();
      if (t < 64) {
        float s = buf[t] + buf[t + 64] + buf[t + 128] + buf[t + 192];
        atomicAdd(&tacc[t], s);
      }
    }
    return;
  }
  int pbid = bid - EB;
  if (pbid < a.NC) {
    int m = 0;
#pragma unroll
    for (int i = 1; i < 6; ++i) if (pbid >= a.tstart[i]) m = i;
    const float* W = a.W[m];
    __hip_bfloat16* Wt = a.Wt[m];
    int K = a.K[m], Nw = a.Nw[m];
    int lt = pbid - a.tstart[m];
    int ntn = Nw >> 6;
    int bk = (lt / ntn) * 32, bn = (lt % ntn) * 64;
    int rn = t & 63, rk = t >> 6;
#pragma unroll
    for (int i = 0; i < 8; ++i)
      tile[rk + i * 4][rn] = W[(size_t)(bk + rk + i * 4) * Nw + bn + rn];
    __syncthreads();
    int wk2 = (t & 15) * 2, wn = t >> 4;
    uint* Wo = (uint*)Wt;
#pragma unroll
    for (int i = 0; i < 4; ++i) {
      int n = wn + i * 16;
      Wo[((size_t)(bn + n) * K + bk + wk2) >> 1] = packbf(tile[wk2][n], tile[wk2 + 1][n]);
    }
  } else if (pbid < a.NC + a.XB) {
    int i4 = (pbid - a.NC) * 256 + t;
    int row = i4 >> 4;
    float4 v = make_float4(0.f, 0.f, 0.f, 0.f);
    if (row < N) v = ((const float4*)x)[i4];
    uint2 p; p.x = packbf(v.x, v.y); p.y = packbf(v.z, v.w);
    ((uint2*)xbf)[i4] = p;
  } else {
    int row = N + (pbid - a.NC - a.XB);
    ((uint*)habf)[(size_t)row * 256 + t] = 0;
    if (t < 64) ((uint*)aggbf)[(size_t)row * 64 + t] = 0;
  }
}

// ---------------- coalesced tiled scan over 8-copy counts + time-combine (block 2) ------
// Block 0: D-array, block 1: S-array. LDS tile of 10240 nodes, 2 tiles.
#define STILE 10240
__global__ __launch_bounds__(1024) void k_scan2c(
    const int* __restrict__ cntD, int* __restrict__ offD, int* __restrict__ coffD,
    const int* __restrict__ cntS, int* __restrict__ offS, int* __restrict__ coffS,
    int n,
    const float* __restrict__ tacc, const float* __restrict__ tW2,
    const float* __restrict__ tb2, const float* __restrict__ fW1,
    const float* __restrict__ fb1, float* __restrict__ cvec, int E) {
  int t = threadIdx.x;
  if (blockIdx.x == 2) {
    __shared__ float tm[128];
    if (t < 128) {
      float inv = 1.f / (float)E;
      float acc = tb2[t];
      for (int k = 0; k < 64; ++k) acc += (tacc[k] * inv) * tW2[k * 128 + t];
      tm[t] = acc;
    }
    __syncthreads();
    if (t < 128) {
      float c = fb1[t];
      for (int k = 0; k < 128; ++k) c += tm[k] * fW1[(128 + k) * 128 + t];
      cvec[t] = c;
    }
    return;
  }
  const int* cnt = blockIdx.x ? cntS : cntD;
  int* off = blockIdx.x ? offS : offD;
  int* coff = blockIdx.x ? coffS : coffD;
  __shared__ uint tl[STILE];
  __shared__ int sums[1024];
  __shared__ int carry_s;
  if (t == 0) carry_s = 0;
  __syncthreads();
  int carry = 0;
  for (int base = 0; base < n; base += STILE) {
    int cntTile = n - base; if (cntTile > STILE) cntTile = STILE;
    // pass A: coalesced per-node totals into LDS
    for (int i = t; i < cntTile; i += 1024) {
      uint s = 0;
#pragma unroll
      for (int c = 0; c < 8; ++c) s += (uint)cnt[(size_t)c * n + base + i];
      tl[i] = s;
    }
    __syncthreads();
    // pass B: per-thread chunk sums (LDS reads), block prefix
    int st = t * (STILE / 1024);
    int loc = 0;
#pragma unroll
    for (int i = 0; i < STILE / 1024; ++i) {
      int idx = st + i;
      if (idx < cntTile) loc += (int)tl[idx];
    }
    sums[t] = loc;
    __syncthreads();
    for (int o = 1; o < 1024; o <<= 1) {
      int v = (t >= o) ? sums[t - o] : 0;
      __syncthreads();
      sums[t] += v;
      __syncthreads();
    }
    int run = carry + sums[t] - loc;
    // write off + stash per-node base back into tl
#pragma unroll
    for (int i = 0; i < STILE / 1024; ++i) {
      int idx = st + i;
      if (idx < cntTile) {
        int v = (int)tl[idx];
        off[base + idx] = run;
        tl[idx] = (uint)run;
        run += v;
      }
    }
    __syncthreads();
    // pass C: coalesced coff per copy
    for (int c = 0; c < 8; ++c) {
      for (int i = t; i < cntTile; i += 1024) {
        uint b = tl[i];
        coff[(size_t)c * n + base + i] = (int)b;
        tl[i] = b + (uint)cnt[(size_t)c * n + base + i];
      }
    }
    __syncthreads();
    if (t == 1023) carry_s = run;
    __syncthreads();
    carry = carry_s;
  }
  if (t == 0) off[n] = carry;
}

// ---------------- bf16 MFMA GEMM, BK=64, EPI1 epilogue, optional embedded CSR-fill ----
__global__ __launch_bounds__(256) void gemm_e1(
    const __hip_bfloat16* __restrict__ A, const __hip_bfloat16* __restrict__ Bt,
    void* __restrict__ Cout, int M, int Nn, int K,
    const float* __restrict__ asrc, const float* __restrict__ adst,
    float* __restrict__ al, float* __restrict__ ar,
    float* __restrict__ C2, const float* __restrict__ bias2,
    int TBx,
    const int* __restrict__ fsrc, const int* __restrict__ fdst, int fE,
    const int* __restrict__ fcoffD, const int* __restrict__ fslotD, int* flstD,
    const int* __restrict__ fcoffS, const int* __restrict__ fslotS, int* flstS)
{
  __shared__ short As0[128 * 32];
  __shared__ short As1[128 * 32];
  __shared__ short Bs0[128 * 32];
  __shared__ short Bs1[128 * 32];
  if ((int)blockIdx.x >= TBx) {
    if (blockIdx.y == 0) {
      int e = ((int)blockIdx.x - TBx) * 256 + (int)threadIdx.x;
      if (e < fE) {
        int d = fdst[e], s = fsrc[e];
        int c = (e >> 8) & 7;
        flstD[fcoffD[(size_t)c * Nn + d] + fslotD[e]] = s;
        flstS[fcoffS[(size_t)c * Nn + s] + fslotS[e]] = d;
      }
    }
    return;
  }
  int tid = threadIdx.x;
  int bm = blockIdx.x * 128;
  int cb = blockIdx.y;
  int bn = cb * 128;
  int w = tid >> 6, l = tid & 63;
  int wr = (w >> 1) * 64, wc = (w & 1) * 64;
  f32x4 acc[4][4] = {};
  const short* Ag = (const short*)A;
  const short* Bg = (const short*)Bt;

  for (int k0 = 0; k0 < K; k0 += 64) {
#pragma unroll
    for (int i = 0; i < 2; ++i) {
      int slot = i * 256 + tid;
      int row = slot >> 2;
      int col = (slot & 3) * 8;
      const short* Arow = Ag + (size_t)(bm + row) * K + k0 + col;
      const short* Brow = Bg + (size_t)(bn + row) * K + k0 + col;
      gload16(Arow, &As0[slot * 8]);
      gload16(Arow + 32, &As1[slot * 8]);
      gload16(Brow, &Bs0[slot * 8]);
      gload16(Brow + 32, &Bs1[slot * 8]);
    }
    __syncthreads();
    {
      bf16x8 af[4], bfr[4];
#pragma unroll
      for (int m = 0; m < 4; ++m)
        af[m] = *(const bf16x8*)&As0[(wr + m * 16 + (l & 15)) * 32 + (l >> 4) * 8];
#pragma unroll
      for (int n = 0; n < 4; ++n)
        bfr[n] = *(const bf16x8*)&Bs0[(wc + n * 16 + (l & 15)) * 32 + (l >> 4) * 8];
#pragma unroll
      for (int m = 0; m < 4; ++m)
#pragma unroll
        for (int n = 0; n < 4; ++n)
          acc[m][n] = __builtin_amdgcn_mfma_f32_16x16x32_bf16(af[m], bfr[n], acc[m][n], 0, 0, 0);
    }
    {
      bf16x8 af[4], bfr[4];
#pragma unroll
      for (int m = 0; m < 4; ++m)
        af[m] = *(const bf16x8*)&As1[(wr + m * 16 + (l & 15)) * 32 + (l >> 4) * 8];
#pragma unroll
      for (int n = 0; n < 4; ++n)
        bfr[n] = *(const bf16x8*)&Bs1[(wc + n * 16 + (l & 15)) * 32 + (l >> 4) * 8];
#pragma unroll
      for (int m = 0; m < 4; ++m)
#pragma unroll
        for (int n = 0; n < 4; ++n)
          acc[m][n] = __builtin_amdgcn_mfma_f32_16x16x32_bf16(af[m], bfr[n], acc[m][n], 0, 0, 0);
    }
    __syncthreads();
  }

  int g = l >> 4, cc = l & 15, cr = g * 4;

  if (cb < 4) {
#pragma unroll
    for (int n = 0; n < 4; ++n) {
      int col = bn + wc + n * 16 + cc;
#pragma unroll
      for (int m = 0; m < 4; ++m) {
#pragma unroll
        for (int r = 0; r < 4; ++r) {
          int gm = bm + wr + m * 16 + cr + r;
          if (gm < M)
            ((__hip_bfloat16*)Cout)[(size_t)gm * 512 + col] = __float2bfloat16(acc[m][n][r]);
        }
      }
    }
    float asv[4], adv[4];
#pragma unroll
    for (int n = 0; n < 4; ++n) {
      int ch = bn + wc + n * 16 + cc;
      asv[n] = asrc[ch]; adv[n] = adst[ch];
    }
    float* spal = (float*)As0;
    float* spar = spal + 256;
#pragma unroll
    for (int m = 0; m < 4; ++m) {
#pragma unroll
      for (int r = 0; r < 4; ++r) {
        float pa = acc[m][0][r] * asv[0] + acc[m][1][r] * asv[1]
                 + acc[m][2][r] * asv[2] + acc[m][3][r] * asv[3];
        float pb = acc[m][0][r] * adv[0] + acc[m][1][r] * adv[1]
                 + acc[m][2][r] * adv[2] + acc[m][3][r] * adv[3];
#pragma unroll
        for (int o = 1; o < 16; o <<= 1) {
          pa += __shfl_xor(pa, o);
          pb += __shfl_xor(pb, o);
        }
        if (cc == 0) {
          int rl = m * 16 + cr + r;
          spal[w * 64 + rl] = pa;
          spar[w * 64 + rl] = pb;
        }
      }
    }
    __syncthreads();
    if ((w & 1) == 0) {
      float av = spal[w * 64 + l] + spal[(w + 1) * 64 + l];
      float rv = spar[w * 64 + l] + spar[(w + 1) * 64 + l];
      int row = bm + wr + l;
      if (row < Nn) { al[row * 4 + cb] = av; ar[row * 4 + cb] = rv; }
    }
  } else {
#pragma unroll
    for (int n = 0; n < 4; ++n) {
      int col2 = wc + n * 16 + cc;
      float bb = bias2[col2];
#pragma unroll
      for (int m = 0; m < 4; ++m) {
#pragma unroll
        for (int r = 0; r < 4; ++r) {
          int gm = bm + wr + m * 16 + cr + r;
          if (gm < Nn) C2[(size_t)gm * 128 + col2] = acc[m][n][r] + bb;
        }
      }
    }
  }
}

// ---------------- fused final MLP: z1 = relu(A@F1+cvec); z2 = z1@F2+fb2; LN; += resid ----
__global__ __launch_bounds__(256) void gemm_ff(
    const __hip_bfloat16* __restrict__ A, const __hip_bfloat16* __restrict__ B1t,
    const __hip_bfloat16* __restrict__ B2t, const float* __restrict__ cvec,
    const float* __restrict__ fb2, const float* __restrict__ lng,
    const float* __restrict__ lnb, float* __restrict__ resid, int M)
{
  __shared__ char ldsraw[32768 + 128 * 136 * 2];
  short* As0 = (short*)ldsraw;
  short* As1 = As0 + 4096;
  short* Bs0 = As1 + 4096;
  short* Bs1 = Bs0 + 4096;
  short* z1s = (short*)(ldsraw + 32768);
  int tid = threadIdx.x;
  int bm = blockIdx.x * 128;
  int w = tid >> 6, l = tid & 63;
  int wr = (w >> 1) * 64, wc = (w & 1) * 64;
  int g = l >> 4, cc = l & 15, cr = g * 4;
  const short* Ag = (const short*)A;
  const short* B1 = (const short*)B1t;
  const short* B2 = (const short*)B2t;
  f32x4 acc[4][4] = {};

  for (int k0 = 0; k0 < 128; k0 += 64) {
#pragma unroll
    for (int i = 0; i < 2; ++i) {
      int slot = i * 256 + tid;
      int row = slot >> 2;
      int col = (slot & 3) * 8;
      const short* Arow = Ag + (size_t)(bm + row) * 128 + k0 + col;
      const short* Brow = B1 + (size_t)row * 128 + k0 + col;
      gload16(Arow, &As0[slot * 8]);
      gload16(Arow + 32, &As1[slot * 8]);
      gload16(Brow, &Bs0[slot * 8]);
      gload16(Brow + 32, &Bs1[slot * 8]);
    }
    __syncthreads();
    {
      bf16x8 af[4], bfr[4];
#pragma unroll
      for (int m = 0; m < 4; ++m)
        af[m] = *(const bf16x8*)&As0[(wr + m * 16 + (l & 15)) * 32 + (l >> 4) * 8];
#pragma unroll
      for (int n = 0; n < 4; ++n)
        bfr[n] = *(const bf16x8*)&Bs0[(wc + n * 16 + (l & 15)) * 32 + (l >> 4) * 8];
#pragma unroll
      for (int m = 0; m < 4; ++m)
#pragma unroll
        for (int n = 0; n < 4; ++n)
          acc[m][n] = __builtin_amdgcn_mfma_f32_16x16x32_bf16(af[m], bfr[n], acc[m][n], 0, 0, 0);
    }
    {
      bf16x8 af[4], bfr[4];
#pragma unroll
      for (int m = 0; m < 4; ++m)
        af[m] = *(const bf16x8*)&As1[(wr + m * 16 + (l & 15)) * 32 + (l >> 4) * 8];
#pragma unroll
      for (int n = 0; n < 4; ++n)
        bfr[n] = *(const bf16x8*)&Bs1[(wc + n * 16 + (l & 15)) * 32 + (l >> 4) * 8];
#pragma unroll
      for (int m = 0; m < 4; ++m)
#pragma unroll
        for (int n = 0; n < 4; ++n)
          acc[m][n] = __builtin_amdgcn_mfma_f32_16x16x32_bf16(af[m], bfr[n], acc[m][n], 0, 0, 0);
    }
    __syncthreads();
  }

#pragma unroll
  for (int n = 0; n < 4; ++n) {
    int col = wc + n * 16 + cc;
    float bb = cvec[col];
#pragma unroll
    for (int m = 0; m < 4; ++m) {
#pragma unroll
      for (int r = 0; r < 4; ++r) {
        int rl = wr + m * 16 + cr + r;
        float v = fmaxf(acc[m][n][r] + bb, 0.f);
        __hip_bfloat16 hb = __float2bfloat16(v);
        z1s[rl * 136 + col] = *(short*)&hb;
      }
    }
  }
#pragma unroll
  for (int m = 0; m < 4; ++m)
#pragma unroll
    for (int n = 0; n < 4; ++n)
      acc[m][n] = (f32x4){0.f, 0.f, 0.f, 0.f};
  __syncthreads();

  for (int k0 = 0; k0 < 128; k0 += 64) {
#pragma unroll
    for (int i = 0; i < 2; ++i) {
      int slot = i * 256 + tid;
      int row = slot >> 2;
      int col = (slot & 3) * 8;
      const short* Brow = B2 + (size_t)row * 128 + k0 + col;
      gload16(Brow, &Bs0[slot * 8]);
      gload16(Brow + 32, &Bs1[slot * 8]);
    }
    __syncthreads();
    {
      bf16x8 af[4], bfr[4];
#pragma unroll
      for (int m = 0; m < 4; ++m)
        af[m] = *(const bf16x8*)&z1s[(wr + m * 16 + (l & 15)) * 136 + k0 + (l >> 4) * 8];
#pragma unroll
      for (int n = 0; n < 4; ++n)
        bfr[n] = *(const bf16x8*)&Bs0[(wc + n * 16 + (l & 15)) * 32 + (l >> 4) * 8];
#pragma unroll
      for (int m = 0; m < 4; ++m)
#pragma unroll
        for (int n = 0; n < 4; ++n)
          acc[m][n] = __builtin_amdgcn_mfma_f32_16x16x32_bf16(af[m], bfr[n], acc[m][n], 0, 0, 0);
    }
    {
      bf16x8 af[4], bfr[4];
#pragma unroll
      for (int m = 0; m < 4; ++m)
        af[m] = *(const bf16x8*)&z1s[(wr + m * 16 + (l & 15)) * 136 + k0 + 32 + (l >> 4) * 8];
#pragma unroll
      for (int n = 0; n < 4; ++n)
        bfr[n] = *(const bf16x8*)&Bs1[(wc + n * 16 + (l & 15)) * 32 + (l >> 4) * 8];
#pragma unroll
      for (int m = 0; m < 4; ++m)
#pragma unroll
        for (int n = 0; n < 4; ++n)
          acc[m][n] = __builtin_amdgcn_mfma_f32_16x16x32_bf16(af[m], bfr[n], acc[m][n], 0, 0, 0);
    }
    __syncthreads();
  }

  float bb[4], gl_[4], gb_[4];
#pragma unroll
  for (int n = 0; n < 4; ++n) {
    int col = wc + n * 16 + cc;
    bb[n] = fb2[col]; gl_[n] = lng[col]; gb_[n] = lnb[col];
  }
  float* ssum = (float*)As0;
  float* ssq = ssum + 256;
  float* smu = ssum + 512;
  float* srs = ssum + 640;
#pragma unroll
  for (int m = 0; m < 4; ++m) {
#pragma unroll
    for (int r = 0; r < 4; ++r) {
      float s = 0.f, q = 0.f;
#pragma unroll
      for (int n = 0; n < 4; ++n) {
        float z = acc[m][n][r] + bb[n];
        s += z; q += z * z;
      }
#pragma unroll
      for (int o = 1; o < 16; o <<= 1) {
        s += __shfl_xor(s, o);
        q += __shfl_xor(q, o);
      }
      if (cc == 0) {
        int rl = m * 16 + cr + r;
        ssum[w * 64 + rl] = s;
        ssq[w * 64 + rl] = q;
      }
    }
  }
  __syncthreads();
  if ((w & 1) == 0) {
    float s = ssum[w * 64 + l] + ssum[(w + 1) * 64 + l];
    float q = ssq[w * 64 + l] + ssq[(w + 1) * 64 + l];
    float mu = s * (1.f / 128.f);
    float var = q * (1.f / 128.f) - mu * mu;
    smu[wr + l] = mu;
    srs[wr + l] = rsqrtf(var + 1e-5f);
  }
  __syncthreads();
#pragma unroll
  for (int m = 0; m < 4; ++m) {
#pragma unroll
    for (int r = 0; r < 4; ++r) {
      int rl = wr + m * 16 + cr + r;
      int gm = bm + rl;
      if (gm < M) {
        float mu = smu[rl], rs = srs[rl];
#pragma unroll
        for (int n = 0; n < 4; ++n) {
          int col = wc + n * 16 + cc;
          float z = acc[m][n][r] + bb[n];
          float y = (z - mu) * rs * gl_[n] + gb_[n] + resid[(size_t)gm * 128 + col];
          resid[(size_t)gm * 128 + col] = y;
        }
      }
    }
  }
}

// ---------------- GAT aggregation: wave per dst node, full-row uint4 gather ----------------
__global__ __launch_bounds__(256) void k_gat_agg(
    const __hip_bfloat16* __restrict__ xl, const float* __restrict__ al,
    const float* __restrict__ ar, const int* __restrict__ off,
    const int* __restrict__ lst, const float* __restrict__ bias,
    __hip_bfloat16* __restrict__ outb, __hip_bfloat16* __restrict__ outh,
    int mode, int N)
{
  __shared__ int   sside[4][64];
  __shared__ float sebuf[4][4][68];
  int w = threadIdx.x >> 6, l = threadIdx.x & 63;
  int d = blockIdx.x * 4 + w;
  bool active = (d < N);
  int base = 0, deg = 0, tot = 0;
  float4 arv = make_float4(0.f, 0.f, 0.f, 0.f);
  if (active) {
    base = off[d]; deg = off[d + 1] - base; tot = deg + 1;
    arv = *(const float4*)(ar + 4 * d);
  }
  int hh = l >> 4;
  float facc[8] = {0.f, 0.f, 0.f, 0.f, 0.f, 0.f, 0.f, 0.f};
  float dn0 = 0.f, dn1 = 0.f, dn2 = 0.f, dn3 = 0.f;
  const uint4* xw = (const uint4*)xl;
  auto fma8 = [&](uint4 pv, float e) {
    facc[0] += e * __uint_as_float(pv.x << 16);
    facc[1] += e * __uint_as_float(pv.x & 0xffff0000u);
    facc[2] += e * __uint_as_float(pv.y << 16);
    facc[3] += e * __uint_as_float(pv.y & 0xffff0000u);
    facc[4] += e * __uint_as_float(pv.z << 16);
    facc[5] += e * __uint_as_float(pv.z & 0xffff0000u);
    facc[6] += e * __uint_as_float(pv.w << 16);
    facc[7] += e * __uint_as_float(pv.w & 0xffff0000u);
  };
  for (int cb = 0; cb < tot; cb += 64) {
    int j = cb + l;
    float e0 = 0.f, e1 = 0.f, e2 = 0.f, e3 = 0.f;
    int sid = 0;
    if (j < tot) {
      sid = (j == deg) ? d : lst[base + j];
      float4 av = *(const float4*)(al + 4 * sid);
      e0 = __expf(lrelu(av.x + arv.x));
      e1 = __expf(lrelu(av.y + arv.y));
      e2 = __expf(lrelu(av.z + arv.z));
      e3 = __expf(lrelu(av.w + arv.w));
      dn0 += e0; dn1 += e1; dn2 += e2; dn3 += e3;
    }
    sside[w][l] = sid;
    sebuf[w][0][l] = e0; sebuf[w][1][l] = e1;
    sebuf[w][2][l] = e2; sebuf[w][3][l] = e3;
    int cnt = tot - cb; if (cnt > 64) cnt = 64;
    int jj = 0;
    for (; jj + 4 <= cnt; jj += 4) {
      int s0 = sside[w][jj], s1 = sside[w][jj + 1];
      int s2 = sside[w][jj + 2], s3 = sside[w][jj + 3];
      float ea = sebuf[w][hh][jj], eb = sebuf[w][hh][jj + 1];
      float ec = sebuf[w][hh][jj + 2], ed = sebuf[w][hh][jj + 3];
      uint4 p0 = xw[(size_t)s0 * 64 + l];
      uint4 p1 = xw[(size_t)s1 * 64 + l];
      uint4 p2 = xw[(size_t)s2 * 64 + l];
      uint4 p3 = xw[(size_t)s3 * 64 + l];
      fma8(p0, ea); fma8(p1, eb); fma8(p2, ec); fma8(p3, ed);
    }
    for (; jj < cnt; ++jj) {
      int s0 = sside[w][jj];
      float ea = sebuf[w][hh][jj];
      uint4 p0 = xw[(size_t)s0 * 64 + l];
      fma8(p0, ea);
    }
  }
#pragma unroll
  for (int o = 1; o < 64; o <<= 1) {
    dn0 += __shfl_xor(dn0, o); dn1 += __shfl_xor(dn1, o);
    dn2 += __shfl_xor(dn2, o); dn3 += __shfl_xor(dn3, o);
  }
  if (!active) return;
  float dsel = hh == 0 ? dn0 : hh == 1 ? dn1 : hh == 2 ? dn2 : dn3;
  float rden = 1.f / dsel;
  if (mode == 0) {
    int c8 = l * 8;
    const float4* bp = (const float4*)(bias + c8);
    float4 b0 = bp[0], b1 = bp[1];
    float vb[8] = {b0.x, b0.y, b0.z, b0.w, b1.x, b1.y, b1.z, b1.w};
    uint4 o4; uint* po = (uint*)&o4;
#pragma unroll
    for (int i = 0; i < 4; ++i) {
      float v0 = fmaxf(facc[2*i]   * rden + vb[2*i],   0.f);
      float v1 = fmaxf(facc[2*i+1] * rden + vb[2*i+1], 0.f);
      po[i] = packbf(v0, v1);
    }
    ((uint4*)outb)[(size_t)d * 64 + l] = o4;
  } else {
#pragma unroll
    for (int i = 0; i < 8; ++i) {
      facc[i] *= rden;
      facc[i] += __shfl_xor(facc[i], 16);
      facc[i] += __shfl_xor(facc[i], 32);
    }
    if (l < 16) {
      int c = l * 8;
      const float4* bp = (const float4*)(bias + c);
      float4 b0 = bp[0], b1 = bp[1];
      float vb[8] = {b0.x, b0.y, b0.z, b0.w, b1.x, b1.y, b1.z, b1.w};
      uint4 o4; uint* po = (uint*)&o4;
#pragma unroll
      for (int i = 0; i < 4; ++i) {
        float v0 = fmaxf(facc[2*i]   * 0.25f + vb[2*i],   0.f);
        float v1 = fmaxf(facc[2*i+1] * 0.25f + vb[2*i+1], 0.f);
        po[i] = packbf(v0, v1);
      }
      ((uint4*)outh)[(size_t)d * 16 + l] = o4;
    }
  }
}

// ---------------- final src-side segment sum (h3 bf16 -> aggbf bf16), 4-deep ----------------
__global__ __launch_bounds__(256) void k_aggsrc(const __hip_bfloat16* __restrict__ h3,
    const int* __restrict__ off, const int* __restrict__ lst,
    __hip_bfloat16* __restrict__ out, int N) {
  int w = threadIdx.x >> 6, l = threadIdx.x & 63;
  int n = blockIdx.x * 4 + w;
  if (n >= N) return;
  const uint* hw = (const uint*)h3;
  uint pv = hw[(size_t)n * 64 + l];
  float a0 = __uint_as_float(pv << 16);
  float a1 = __uint_as_float(pv & 0xffff0000u);
  float b0 = 0.f, b1 = 0.f, c0 = 0.f, c1 = 0.f, d0 = 0.f, d1 = 0.f;
  int b = off[n], e = off[n + 1];
  int j = b;
  for (; j + 4 <= e; j += 4) {
    int s0 = lst[j], s1 = lst[j + 1], s2 = lst[j + 2], s3 = lst[j + 3];
    uint q0 = hw[(size_t)s0 * 64 + l];
    uint q1 = hw[(size_t)s1 * 64 + l];
    uint q2 = hw[(size_t)s2 * 64 + l];
    uint q3 = hw[(size_t)s3 * 64 + l];
    a0 += __uint_as_float(q0 << 16); a1 += __uint_as_float(q0 & 0xffff0000u);
    b0 += __uint_as_float(q1 << 16); b1 += __uint_as_float(q1 & 0xffff0000u);
    c0 += __uint_as_float(q2 << 16); c1 += __uint_as_float(q2 & 0xffff0000u);
    d0 += __uint_as_float(q3 << 16); d1 += __uint_as_float(q3 & 0xffff0000u);
  }
  for (; j < e; ++j) {
    uint q = hw[(size_t)lst[j] * 64 + l];
    a0 += __uint_as_float(q << 16);
    a1 += __uint_as_float(q & 0xffff0000u);
  }
  ((uint*)out)[(size_t)n * 64 + l] = packbf((a0 + b0) + (c0 + d0), (a1 + b1) + (c1 + d1));
}

extern "C" void kernel_launch(void* const* d_in, const int* in_sizes, int n_in,
                              void* d_out, int out_size, void* d_ws, size_t ws_size,
                              hipStream_t stream) {
  (void)n_in; (void)out_size; (void)ws_size;
  const float* x   = (const float*)d_in[0];
  const float* et  = (const float*)d_in[1];
  const float* W1  = (const float*)d_in[2];
  const float* as1 = (const float*)d_in[3];
  const float* ad1 = (const float*)d_in[4];
  const float* b1  = (const float*)d_in[5];
  const float* W2  = (const float*)d_in[6];
  const float* as2 = (const float*)d_in[7];
  const float* ad2 = (const float*)d_in[8];
  const float* b2  = (const float*)d_in[9];
  const float* W3  = (const float*)d_in[10];
  const float* as3 = (const float*)d_in[11];
  const float* ad3 = (const float*)d_in[12];
  const float* b3  = (const float*)d_in[13];
  const float* tW1 = (const float*)d_in[14];
  const float* tb1 = (const float*)d_in[15];
  const float* tW2 = (const float*)d_in[16];
  const float* tb2 = (const float*)d_in[17];
  const float* fW1 = (const float*)d_in[18];
  const float* fb1 = (const float*)d_in[19];
  const float* fW2 = (const float*)d_in[20];
  const float* fb2 = (const float*)d_in[21];
  const float* lng = (const float*)d_in[22];
  const float* lnb = (const float*)d_in[23];
  const float* rW  = (const float*)d_in[24];
  const float* rb  = (const float*)d_in[25];
  const int*   ei  = (const int*)d_in[26];
  const int N = in_sizes[0] / 64;     // 20000
  const int E = in_sizes[26] / 2;     // 320000
  const int Mp = ((N + 127) / 128) * 128;  // 20096
  const int* src = ei;
  const int* dst = ei + E;

  char* cur = (char*)d_ws;
  auto carve = [&](size_t bytes) { char* p = cur; cur += (bytes + 255) & ~(size_t)255; return p; };
  __hip_bfloat16* xbf  = (__hip_bfloat16*)carve((size_t)Mp * 64 * 2);
  __hip_bfloat16* habf = (__hip_bfloat16*)carve((size_t)Mp * 512 * 2);
  __hip_bfloat16* xlbf = (__hip_bfloat16*)carve((size_t)Mp * 512 * 2);
  __hip_bfloat16* wtCat= (__hip_bfloat16*)carve((size_t)640 * 64 * 2);  // [W1t(512); rWt(128)]
  __hip_bfloat16* wt2  = (__hip_bfloat16*)carve((size_t)512 * 512 * 2);
  __hip_bfloat16* wt3  = (__hip_bfloat16*)carve((size_t)512 * 512 * 2);
  __hip_bfloat16* wtF1 = (__hip_bfloat16*)carve((size_t)128 * 128 * 2);
  __hip_bfloat16* wtF2 = (__hip_bfloat16*)carve((size_t)128 * 128 * 2);
  __hip_bfloat16* aggbf= (__hip_bfloat16*)carve((size_t)Mp * 128 * 2);
  __hip_bfloat16* h3   = (__hip_bfloat16*)carve((size_t)N * 128 * 2);
  float* al   = (float*)carve((size_t)N * 4 * 4);
  float* ar   = (float*)carve((size_t)N * 4 * 4);
  float* cvec = (float*)carve(128 * 4);
  int* offD = (int*)carve((size_t)(N + 1) * 4);
  int* offS = (int*)carve((size_t)(N + 1) * 4);
  int* lstD = (int*)carve((size_t)E * 4);
  int* lstS = (int*)carve((size_t)E * 4);
  int* slotD = (int*)carve((size_t)E * 4);
  int* slotS = (int*)carve((size_t)E * 4);
  int* coffD = (int*)carve((size_t)8 * N * 4);
  int* coffS = (int*)carve((size_t)8 * N * 4);
  char* zstart = cur;
  int* cntD = (int*)carve((size_t)8 * N * 4);
  int* cntS = (int*)carve((size_t)8 * N * 4);
  float* tacc = (float*)carve(64 * 4);
  size_t zbytes = (size_t)(cur - zstart);
  float* xres = (float*)d_out;

  hipMemsetAsync(zstart, 0, zbytes, stream);

  const int EB = (E + 255) / 256;   // 1250
  PrepArgs pa;
  {
    int ts = 0;
    auto setd = [&](int i, const float* W, __hip_bfloat16* Wt, int K, int Nw) {
      pa.W[i] = W; pa.Wt[i] = Wt; pa.K[i] = K; pa.Nw[i] = Nw; pa.tstart[i] = ts;
      ts += (K / 32) * (Nw / 64);
    };
    setd(0, W1, wtCat, 64, 512);
    setd(1, W2, wt2, 512, 512);
    setd(2, W3, wt3, 512, 512);
    setd(3, rW, wtCat + (size_t)512 * 64, 64, 128);
    setd(4, fW1, wtF1, 128, 128);
    setd(5, fW2, wtF2, 128, 128);
    pa.NC = ts;
    pa.XB = Mp / 16;
    int grid = EB + pa.NC + pa.XB + (Mp - N);
    k_build<<<grid, 256, 0, stream>>>(src, dst, E, cntD, cntS, slotD, slotS,
                                      et, tW1, tb1, tacc,
                                      pa, x, xbf, habf, aggbf, N, Mp, EB);
  }
  k_scan2c<<<3, 1024, 0, stream>>>(cntD, offD, coffD, cntS, offS, coffS, N,
                                   tacc, tW2, tb2, fW1, fb1, cvec, E);

  const int TB = Mp / 128;  // 157
  const int GB = (N + 3) / 4;
  const int BIG = 1 << 30;

  // layer 1 GEMM (+x_res in col-block 4) with embedded atomic-free CSR fill
  gemm_e1<<<dim3(TB + EB, 5), 256, 0, stream>>>(xbf, wtCat, xlbf, Mp, N, 64,
      as1, ad1, al, ar, xres, rb,
      TB, src, dst, E, coffD, slotD, lstD, coffS, slotS, lstS);
  k_gat_agg<<<GB, 256, 0, stream>>>(xlbf, al, ar, offD, lstD, b1, habf, nullptr, 0, N);
  // layer 2
  gemm_e1<<<dim3(TB, 4), 256, 0, stream>>>(habf, wt2, xlbf, Mp, N, 512,
      as2, ad2, al, ar, nullptr, nullptr,
      BIG, nullptr, nullptr, 0, nullptr, nullptr, nullptr, nullptr, nullptr, nullptr);
  k_gat_agg<<<GB, 256, 0, stream>>>(xlbf, al, ar, offD, lstD, b2, habf, nullptr, 0, N);
  // layer 3 (head-mean -> h3)
  gemm_e1<<<dim3(TB, 4), 256, 0, stream>>>(habf, wt3, xlbf, Mp, N, 512,
      as3, ad3, al, ar, nullptr, nullptr,
      BIG, nullptr, nullptr, 0, nullptr, nullptr, nullptr, nullptr, nullptr, nullptr);
  k_gat_agg<<<GB, 256, 0, stream>>>(xlbf, al, ar, offD, lstD, b3, nullptr, h3, 1, N);

  // agg = segment_sum(h3[dst], src)
  k_aggsrc<<<GB, 256, 0, stream>>>(h3, offS, lstS, aggbf, N);

  // fused final MLP + LN + residual -> d_out
  gemm_ff<<<TB, 256, 0, stream>>>(aggbf, wtF1, wtF2, cvec, fb2, lng, lnb, xres, N);
}